// Round 8
// baseline (192.521 us; speedup 1.0000x reference)
//
#include <hip/hip_runtime.h>
#include <hip/hip_fp16.h>

#define TPB 256
#define CAP 16384          // slack entries per 256-node bucket (padded fill ~5100)
#define CAPSH 14           // log2(CAP)
#define SC_BLOCKS 256      // scatter blocks: contiguous pairs chunks per bucket

typedef __attribute__((ext_vector_type(8))) float f32x8;
typedef __attribute__((ext_vector_type(8))) unsigned short u16x8;
typedef __attribute__((ext_vector_type(4))) unsigned int u32x4;
typedef __attribute__((ext_vector_type(2))) _Float16 h16x2;
typedef __attribute__((ext_vector_type(8))) _Float16 h16x8;
typedef __attribute__((ext_vector_type(4))) float f32x4;

// Identity used: dis⊙(x@W) = (dis⊙x)@W and Agg(z@W) = (Agg z)@W, so each
// layer is gather(z) -> mm -> relu, with z = fp16(dis ⊙ activation).
// Buckets: 256 nodes each (dst>>8); bucket b owns pairs/csr[b*CAP..).
// CSR runs padded to a multiple of 8 with index N (zero row).
// meta[v] = { (offset<<8) | nbatches, bitcast(dis) }.
// Lessons: R2 direct CSR = write-allocate blowup. R3/R4/R6 micro-fixes
// neutral. R7 pipelined gather small win. Instruction accounting: the
// VALU/LDS shfl-mm (128 ds_read_b128 + 512 FMA per wave for 8 nodes) was
// ~60% of layer time. This round: MFMA mm. 16 nodes/wave; W held as
// 16x16x32_f16 B-fragments in 32 VGPRs (built once/block from LDS); 8 MFMA
// replace the whole shfl-mm. Gather emits the A-fragment layout directly:
// lane l (q=l>>4, r=l&15) owns node r's feature slices [8q,8q+8) and
// [32+8q,..) in f32, converted to f16 for MFMA (accum f32). C layout
// (doc-verified): col=lane&15, row=(lane>>4)*4+reg. absmax expected ~1e-3
// (s,W fp16-quantized for MFMA).

__device__ __forceinline__ int ld_idx(const void* p, long long i, int is64) {
    return is64 ? (int)((const long long*)p)[i] : ((const int*)p)[i];
}

__device__ __forceinline__ ushort4 f4_to_h4(float4 v) {
    ushort4 r;
    r.x = __half_as_ushort(__float2half_rn(v.x));
    r.y = __half_as_ushort(__float2half_rn(v.y));
    r.z = __half_as_ushort(__float2half_rn(v.z));
    r.w = __half_as_ushort(__float2half_rn(v.w));
    return r;
}

// ---------------------------------------------------------------------------
// Scatter: pass A histograms dst buckets (LDS), one global atomic per
// (block,bucket) reserves a contiguous chunk, pass B re-reads edges (L2/L3
// warm) and writes pairs into the chunk. gcur must be zeroed.
// ---------------------------------------------------------------------------
__global__ __launch_bounds__(TPB) void p3_scatter(const void* __restrict__ ei,
                                                  long long E,
                                                  int* __restrict__ gcur,
                                                  int* __restrict__ pairs) {
    __shared__ int cnt[TPB];
    __shared__ int cur2[TPB];
    __shared__ int s_is64;
    int t = threadIdx.x;
    if (t < 64) {
        const unsigned int* w = (const unsigned int*)ei;
        unsigned long long m = __ballot(w[2 * t + 1] != 0u);
        if (t == 0) s_is64 = (m == 0ull) ? 1 : 0;
    }
    cnt[t] = 0;
    __syncthreads();
    const int is64 = s_is64;
    long long chunk = (E + SC_BLOCKS - 1) / SC_BLOCKS;
    long long s0 = (long long)blockIdx.x * chunk;
    long long s1 = (s0 + chunk < E) ? s0 + chunk : E;

    for (long long e = s0 + t; e < s1; e += TPB) {       // pass A: count
        int d = ld_idx(ei, E + e, is64);
        atomicAdd(&cnt[d >> 8], 1);
    }
    __syncthreads();
    if (cnt[t]) cur2[t] = (t << CAPSH) + atomicAdd(&gcur[t], cnt[t]);
    __syncthreads();
    for (long long e = s0 + t; e < s1; e += TPB) {       // pass B: write
        int sv = ld_idx(ei, e, is64);
        int d  = ld_idx(ei, E + e, is64);
        int pos = atomicAdd(&cur2[d >> 8], 1);
        pairs[pos] = (sv << 8) | (d & 255);
    }
}

// ---------------------------------------------------------------------------
// One block per bucket: degree count (LDS atomics) -> pad-to-8 256-wide scan
// -> meta, csr scatter via LDS cursors + pad with index N, then
// z0 = fp16(dis * x) for this bucket's 256 nodes. Block 0 zeroes z0 row N.
// ---------------------------------------------------------------------------
__global__ __launch_bounds__(TPB) void p4_fill(const int* __restrict__ pairs,
                                               const int* __restrict__ gcur,
                                               const float* __restrict__ x,
                                               int2* __restrict__ meta,
                                               int* __restrict__ csr,
                                               ushort4* __restrict__ z0, int N) {
    __shared__ int ldeg[TPB];
    __shared__ int ssc[TPB];
    __shared__ int cur[TPB];
    __shared__ float fdis[TPB];
    int t = threadIdx.x;
    int b = blockIdx.x;
    int base = b << CAPSH;
    int ecnt = gcur[b];                          // real edges in this bucket
    ldeg[t] = 0;
    __syncthreads();
    for (int e = base + t; e < base + ecnt; e += TPB)
        atomicAdd(&ldeg[pairs[e] & 255], 1);
    __syncthreads();
    int dv = ldeg[t];
    int pv = (dv + 7) & ~7;                      // padded to multiple of 8
    ssc[t] = pv;
    __syncthreads();
    for (int off = 1; off < TPB; off <<= 1) {
        int u = 0;
        if (t >= off) u = ssc[t - off];
        __syncthreads();
        ssc[t] += u;
        __syncthreads();
    }
    int o = base + ssc[t] - pv;                  // absolute padded offset
    cur[t] = o;
    float dd = rsqrtf((float)(dv + 1));          // +1 self loop
    fdis[t] = dd;
    int node = (b << 8) + t;
    if (node < N)
        meta[node] = make_int2((o << 8) | (pv >> 3), __float_as_int(dd));
    __syncthreads();
    for (int e = base + t; e < base + ecnt; e += TPB) {
        int p = pairs[e];
        int pos = atomicAdd(&cur[p & 255], 1);
        csr[pos] = p >> 8;
    }
    for (int e = o + dv; e < o + pv; ++e) csr[e] = N;   // pad with zero row

    // z0 conversion: 16 passes, 16 nodes each, coalesced float4 reads.
    int ni = t >> 4, c = t & 15;
    for (int p = 0; p < 16; ++p) {
        int nd = (b << 8) + p * 16 + ni;
        if (nd < N) {
            float dvv = fdis[p * 16 + ni];
            float4 h = ((const float4*)x)[(size_t)nd * 16 + c];
            float4 r = {h.x * dvv, h.y * dvv, h.z * dvv, h.w * dvv};
            z0[(size_t)nd * 16 + c] = f4_to_h4(r);
        }
    }
    if (b == 0 && t < 16) z0[(size_t)N * 16 + t] = make_ushort4(0, 0, 0, 0);
}

// ---------------------------------------------------------------------------
// Gather building blocks
// ---------------------------------------------------------------------------

#if __has_builtin(__builtin_amdgcn_fdot2) && __has_builtin(__builtin_amdgcn_perm)
#define GCN_DOT2 1
#else
#define GCN_DOT2 0
#endif

// Accumulate the 8 features of TWO fp16 row-chunks into f32 acc (fdot2 path
// halves VALU; f32 accumulation preserved). Same pairing order as R7.
__device__ __forceinline__ void accum_row_pair(const u16x8& ra, const u16x8& rb,
                                               f32x8& acc) {
#if GCN_DOT2
    u32x4 a = __builtin_bit_cast(u32x4, ra);
    u32x4 b = __builtin_bit_cast(u32x4, rb);
    const h16x2 one = {(_Float16)1.0f, (_Float16)1.0f};
    #pragma unroll
    for (int j = 0; j < 4; ++j) {
        unsigned p0 = __builtin_amdgcn_perm(a[j], b[j], 0x05040100u); // h0 pair
        unsigned p1 = __builtin_amdgcn_perm(a[j], b[j], 0x07060302u); // h1 pair
        acc[2 * j]     = __builtin_amdgcn_fdot2(__builtin_bit_cast(h16x2, p0),
                                                one, acc[2 * j], false);
        acc[2 * j + 1] = __builtin_amdgcn_fdot2(__builtin_bit_cast(h16x2, p1),
                                                one, acc[2 * j + 1], false);
    }
#else
    #pragma unroll
    for (int i = 0; i < 8; ++i)
        acc[i] += __half2float(__ushort_as_half(ra[i])) +
                  __half2float(__ushort_as_half(rb[i]));
#endif
}

// MFMA-layout cooperative gather: node r of the wave is owned by lanes
// {r, r+16, r+32, r+48}; lane (q=l>>4) accumulates feature slices
// [8q,8q+8) (lo) and [32+8q,+8) (hi) = row chunks q and q+4 (16 B each).
// Per batch: 4 lanes read int2 csr (8 idx), broadcast within the node's
// lane quad (uniform trip count), 16 independent 16-B row-chunk loads.
__device__ __forceinline__ void gather_mfma(const u16x8* __restrict__ z,
                                            const int* __restrict__ csr,
                                            int start, int nbatch, int q, int r,
                                            f32x8& lo, f32x8& hi) {
    const int2* csr2 = (const int2*)csr;
    int ib = (start >> 1) + q;
    int2 ip = (nbatch > 0) ? csr2[ib] : make_int2(0, 0);
    for (int bt = 0; bt < nbatch; ++bt) {
        int2 ipn = (bt + 1 < nbatch) ? csr2[ib + (bt + 1) * 4] : make_int2(0, 0);
        int s0 = __shfl(ip.x, r);
        int s1 = __shfl(ip.y, r);
        int s2 = __shfl(ip.x, r + 16);
        int s3 = __shfl(ip.y, r + 16);
        int s4 = __shfl(ip.x, r + 32);
        int s5 = __shfl(ip.y, r + 32);
        int s6 = __shfl(ip.x, r + 48);
        int s7 = __shfl(ip.y, r + 48);
        u16x8 l0 = z[(size_t)s0 * 8 + q], h0 = z[(size_t)s0 * 8 + 4 + q];
        u16x8 l1 = z[(size_t)s1 * 8 + q], h1 = z[(size_t)s1 * 8 + 4 + q];
        u16x8 l2 = z[(size_t)s2 * 8 + q], h2 = z[(size_t)s2 * 8 + 4 + q];
        u16x8 l3 = z[(size_t)s3 * 8 + q], h3 = z[(size_t)s3 * 8 + 4 + q];
        u16x8 l4 = z[(size_t)s4 * 8 + q], h4 = z[(size_t)s4 * 8 + 4 + q];
        u16x8 l5 = z[(size_t)s5 * 8 + q], h5 = z[(size_t)s5 * 8 + 4 + q];
        u16x8 l6 = z[(size_t)s6 * 8 + q], h6 = z[(size_t)s6 * 8 + 4 + q];
        u16x8 l7 = z[(size_t)s7 * 8 + q], h7 = z[(size_t)s7 * 8 + 4 + q];
        accum_row_pair(l0, l1, lo); accum_row_pair(h0, h1, hi);
        accum_row_pair(l2, l3, lo); accum_row_pair(h2, h3, hi);
        accum_row_pair(l4, l5, lo); accum_row_pair(h4, h5, hi);
        accum_row_pair(l6, l7, lo); accum_row_pair(h6, h7, hi);
        ip = ipn;
    }
}

// Build W B-fragments for the 4 N-tiles x 2 K-steps of a 16x16x32_f16 GEMM.
// B'[kk][j] for tile (jt,ks): lane l (q=l>>4, r=l&15) holds element i =
// W[ks*32 + 8q + i][16*jt + r]. One-time per block from the f32 LDS stage.
__device__ __forceinline__ void build_wfrags(const float* __restrict__ Ws,
                                             int q, int r, h16x8 wf[4][2]) {
    #pragma unroll
    for (int jt = 0; jt < 4; ++jt)
        #pragma unroll
        for (int ks = 0; ks < 2; ++ks)
            #pragma unroll
            for (int i = 0; i < 8; ++i)
                wf[jt][ks][i] =
                    (_Float16)Ws[(ks * 32 + q * 8 + i) * 64 + jt * 16 + r];
}

// ---------------------------------------------------------------------------
// Layer: s = z_v + Agg z_u (gather, MFMA A-layout); u = S @ W via 8 MFMA;
// zout = fp16(dis*relu(dis*u+b)). 64 nodes/block (16/wave), W frags in VGPR.
// ---------------------------------------------------------------------------
__global__ __launch_bounds__(TPB, 4) void layer_mm(const u16x8* __restrict__ z,
                                                const int* __restrict__ csr,
                                                const int2* __restrict__ meta,
                                                const float* __restrict__ b,
                                                const float* __restrict__ W,
                                                u16x8* __restrict__ zout, int n) {
    __shared__ float Ws[64 * 64];
    int t = threadIdx.x;
    float4* Ws4 = (float4*)Ws;
    const float4* W4g = (const float4*)W;
    #pragma unroll
    for (int i = 0; i < 4; ++i) Ws4[t + i * TPB] = W4g[t + i * TPB];

    if (blockIdx.x == 0 && t < 8) {              // zero row N for next layer
        u16x8 zz = {0, 0, 0, 0, 0, 0, 0, 0};
        zout[(size_t)n * 8 + t] = zz;
    }

    int wave = t >> 6, lane = t & 63;
    int q = lane >> 4, r = lane & 15;
    int base = blockIdx.x * 64 + wave * 16;
    int node = base + r;
    f32x8 lo = {0.f, 0.f, 0.f, 0.f, 0.f, 0.f, 0.f, 0.f};
    f32x8 hi = {0.f, 0.f, 0.f, 0.f, 0.f, 0.f, 0.f, 0.f};
    int start = 0, nbatch = 0;
    if (node < n) {
        int2 m = meta[node];
        start = ((unsigned)m.x) >> 8;
        nbatch = m.x & 255;
        u16x8 v0 = z[(size_t)node * 8 + q];      // self-loop term z_v
        u16x8 v1 = z[(size_t)node * 8 + 4 + q];
        #pragma unroll
        for (int i = 0; i < 8; ++i) {
            lo[i] = __half2float(__ushort_as_half(v0[i]));
            hi[i] = __half2float(__ushort_as_half(v1[i]));
        }
    }
    gather_mfma(z, csr, start, nbatch, q, r, lo, hi);
    __syncthreads();                             // Ws fully staged

    h16x8 wf[4][2];
    build_wfrags(Ws, q, r, wf);
    h16x8 a0, a1;
    #pragma unroll
    for (int i = 0; i < 8; ++i) {
        a0[i] = (_Float16)lo[i];
        a1[i] = (_Float16)hi[i];
    }
    f32x4 zero4 = {0.f, 0.f, 0.f, 0.f};
    f32x4 acc[4] = {zero4, zero4, zero4, zero4};
    #pragma unroll
    for (int jt = 0; jt < 4; ++jt) {
        acc[jt] = __builtin_amdgcn_mfma_f32_16x16x32_f16(a0, wf[jt][0], acc[jt], 0, 0, 0);
        acc[jt] = __builtin_amdgcn_mfma_f32_16x16x32_f16(a1, wf[jt][1], acc[jt], 0, 0, 0);
    }

    // Epilogue: C layout col = 16*jt + r, row = q*4 + i (doc-verified).
    float dvv[4];
    #pragma unroll
    for (int i = 0; i < 4; ++i) {
        int nd = base + q * 4 + i;
        dvv[i] = (nd < n) ? __int_as_float(meta[nd].y) : 0.f;
    }
    #pragma unroll
    for (int jt = 0; jt < 4; ++jt) {
        float bv = b[jt * 16 + r];
        #pragma unroll
        for (int i = 0; i < 4; ++i) {
            int nd = base + q * 4 + i;
            if (nd < n) {
                float val = fmaxf(fmaf(dvv[i], acc[jt][i], bv), 0.f) * dvv[i];
                ((unsigned short*)zout)[(size_t)nd * 64 + jt * 16 + r] =
                    __half_as_ushort(__float2half_rn(val));
            }
        }
    }
}

// ---------------------------------------------------------------------------
// Final: s = gather(z2); h = relu(dis*(s@W2)+b2) (MFMA); h staged to LDS in
// A-layout; out = h @ linW + linb via one zero-padded 16x16x32 MFMA tile.
// ---------------------------------------------------------------------------
__global__ __launch_bounds__(TPB, 4) void layer_final(const u16x8* __restrict__ z,
                                                   const int* __restrict__ csr,
                                                   const int2* __restrict__ meta,
                                                   const float* __restrict__ b,
                                                   const float* __restrict__ W,
                                                   const float* __restrict__ Wl,
                                                   const float* __restrict__ bl,
                                                   float* __restrict__ out, int n) {
    __shared__ float Ws[64 * 64];
    __shared__ float Wls[64 * 8];
    __shared__ float bls[8];
    __shared__ __align__(16) _Float16 hbuf[4][16][64];
    int t = threadIdx.x;
    float4* Ws4 = (float4*)Ws;
    const float4* W4g = (const float4*)W;
    #pragma unroll
    for (int i = 0; i < 4; ++i) Ws4[t + i * TPB] = W4g[t + i * TPB];
    if (t < 128) ((float4*)Wls)[t] = ((const float4*)Wl)[t];
    if (t < 8) bls[t] = bl[t];

    int wave = t >> 6, lane = t & 63;
    int q = lane >> 4, r = lane & 15;
    int base = blockIdx.x * 64 + wave * 16;
    int node = base + r;
    f32x8 lo = {0.f, 0.f, 0.f, 0.f, 0.f, 0.f, 0.f, 0.f};
    f32x8 hi = {0.f, 0.f, 0.f, 0.f, 0.f, 0.f, 0.f, 0.f};
    int start = 0, nbatch = 0;
    if (node < n) {
        int2 m = meta[node];
        start = ((unsigned)m.x) >> 8;
        nbatch = m.x & 255;
        u16x8 v0 = z[(size_t)node * 8 + q];
        u16x8 v1 = z[(size_t)node * 8 + 4 + q];
        #pragma unroll
        for (int i = 0; i < 8; ++i) {
            lo[i] = __half2float(__ushort_as_half(v0[i]));
            hi[i] = __half2float(__ushort_as_half(v1[i]));
        }
    }
    gather_mfma(z, csr, start, nbatch, q, r, lo, hi);
    __syncthreads();                             // Ws/Wls/bls staged

    h16x8 wf[4][2];
    build_wfrags(Ws, q, r, wf);
    h16x8 a0, a1;
    #pragma unroll
    for (int i = 0; i < 8; ++i) {
        a0[i] = (_Float16)lo[i];
        a1[i] = (_Float16)hi[i];
    }
    f32x4 zero4 = {0.f, 0.f, 0.f, 0.f};
    f32x4 acc[4] = {zero4, zero4, zero4, zero4};
    #pragma unroll
    for (int jt = 0; jt < 4; ++jt) {
        acc[jt] = __builtin_amdgcn_mfma_f32_16x16x32_f16(a0, wf[jt][0], acc[jt], 0, 0, 0);
        acc[jt] = __builtin_amdgcn_mfma_f32_16x16x32_f16(a1, wf[jt][1], acc[jt], 0, 0, 0);
    }

    // h = relu(dv*u + b) -> LDS (A-layout staging for second mm).
    float dvv[4];
    #pragma unroll
    for (int i = 0; i < 4; ++i) {
        int nd = base + q * 4 + i;
        dvv[i] = (nd < n) ? __int_as_float(meta[nd].y) : 0.f;
    }
    #pragma unroll
    for (int jt = 0; jt < 4; ++jt) {
        float bv = b[jt * 16 + r];
        #pragma unroll
        for (int i = 0; i < 4; ++i) {
            float hv = fmaxf(fmaf(dvv[i], acc[jt][i], bv), 0.f);
            hbuf[wave][q * 4 + i][jt * 16 + r] = (_Float16)hv;
        }
    }

    // second mm (64 -> 8): one 16x16x32 tile pair, cols 8..15 zero-padded.
    h16x8 wl2[2];
    #pragma unroll
    for (int ks = 0; ks < 2; ++ks)
        #pragma unroll
        for (int i = 0; i < 8; ++i)
            wl2[ks][i] = (r < 8) ? (_Float16)Wls[(ks * 32 + q * 8 + i) * 8 + r]
                                 : (_Float16)0.f;
    h16x8 a20 = *(const h16x8*)&hbuf[wave][r][q * 8];
    h16x8 a21 = *(const h16x8*)&hbuf[wave][r][32 + q * 8];
    f32x4 acc2 = zero4;
    acc2 = __builtin_amdgcn_mfma_f32_16x16x32_f16(a20, wl2[0], acc2, 0, 0, 0);
    acc2 = __builtin_amdgcn_mfma_f32_16x16x32_f16(a21, wl2[1], acc2, 0, 0, 0);
    if (r < 8) {
        float blv = bls[r];
        #pragma unroll
        for (int i = 0; i < 4; ++i) {
            int nd = base + q * 4 + i;
            if (nd < n) out[(size_t)nd * 8 + r] = acc2[i] + blv;
        }
    }
}

extern "C" void kernel_launch(void* const* d_in, const int* in_sizes, int n_in,
                              void* d_out, int out_size, void* d_ws, size_t ws_size,
                              hipStream_t stream) {
    const float* x  = (const float*)d_in[0];
    const void*  ei = d_in[1];
    const float* W0 = (const float*)d_in[2];
    const float* b0 = (const float*)d_in[3];
    const float* W1 = (const float*)d_in[4];
    const float* b1 = (const float*)d_in[5];
    const float* W2 = (const float*)d_in[6];
    const float* b2 = (const float*)d_in[7];
    const float* Wl = (const float*)d_in[8];
    const float* bl = (const float*)d_in[9];

    const long long E = in_sizes[1] / 2;                 // 800000
    const int dh = in_sizes[3];                          // 64
    const int din = in_sizes[2] / dh;                    // 64
    const int N = in_sizes[0] / din;                     // 50000
    const int nb = (N + 255) >> 8;                       // 196 buckets

    // Workspace carve (256-aligned): ~39 MB total
    char* ws = (char*)d_ws;
    size_t off = 0;
    auto alloc = [&](size_t bytes) -> char* {
        char* r = ws + off;
        off += (bytes + 255) & ~(size_t)255;
        return r;
    };
    int*   gcur    = (int*)  alloc(1024);
    int2*  meta    = (int2*) alloc((size_t)N * 8);
    int*   pairs   = (int*)  alloc((size_t)nb * CAP * 4);       // 12.8 MB
    int*   csr     = (int*)  alloc((size_t)nb * CAP * 4);       // 12.8 MB
    u16x8* zbA     = (u16x8*)alloc((size_t)(N + 1) * 64 * 2);   // fp16 rows (+zero row)
    u16x8* zbB     = (u16x8*)alloc((size_t)(N + 1) * 64 * 2);

    // --- preprocessing ---
    hipMemsetAsync(gcur, 0, 256 * sizeof(int), stream);
    p3_scatter<<<SC_BLOCKS, TPB, 0, stream>>>(ei, E, gcur, pairs);
    p4_fill<<<nb, TPB, 0, stream>>>(pairs, gcur, x, meta, csr,
                                    (ushort4*)zbA, N);

    // --- 3 layers: gather -> MFMA mm -> relu ---
    const int gL = (N + 63) / 64;                        // 782 (64 nodes/block)
    layer_mm<<<gL, TPB, 0, stream>>>(zbA, csr, meta, b0, W0, zbB, N);
    layer_mm<<<gL, TPB, 0, stream>>>(zbB, csr, meta, b1, W1, zbA, N);
    layer_final<<<gL, TPB, 0, stream>>>(zbA, csr, meta, b2, W2, Wl, bl,
                                        (float*)d_out, N);
}

// Round 9
// 187.770 us; speedup vs baseline: 1.0253x; 1.0253x over previous
//
#include <hip/hip_runtime.h>
#include <hip/hip_fp16.h>

#define TPB 256
#define CAP 16384          // slack entries per 256-node bucket (padded fill ~5100)
#define CAPSH 14           // log2(CAP)
#define SC_BLOCKS 256      // scatter blocks: contiguous pairs chunks per bucket

typedef __attribute__((ext_vector_type(8))) float f32x8;
typedef __attribute__((ext_vector_type(8))) unsigned short u16x8;
typedef __attribute__((ext_vector_type(4))) unsigned int u32x4;
typedef __attribute__((ext_vector_type(2))) _Float16 h16x2;

// Identity used: dis⊙(x@W) = (dis⊙x)@W and Agg(z@W) = (Agg z)@W, so each
// layer is gather(z) -> mm -> relu, with z = fp16(dis ⊙ activation).
// Buckets: 256 nodes each (dst>>8); bucket b owns pairs/csr[b*CAP..).
// CSR runs padded to a multiple of 8 with index N (zero row).
// meta[v] = { (offset<<8) | nbatches, bitcast(dis) }.
// Lessons: R2 direct CSR = write-allocate blowup. R3/R4/R6 micro-fixes
// neutral. R7 pipelined gather+fdot2 = best (185.0us). R8 MFMA mm = 192.5:
// layer time invariant under mm-engine swap -> no single pipe saturated;
// the constraint is PHASE LOCKSTEP: the Ws-staging barrier sat AFTER the
// gather, forcing all 4 waves to drain gathers (max), then burst the mm's
// LDS reads simultaneously (LDS idle during gather, oversubscribed during
// mm). This round (base=R7): barrier moved to right after the Ws staging
// stores -- each wave then flows gather->mm independently, so VMEM-phase
// waves overlap LDS-phase waves on the CU (m114 co-issue). No arithmetic
// change: absmax must be bit-identical.

__device__ __forceinline__ int ld_idx(const void* p, long long i, int is64) {
    return is64 ? (int)((const long long*)p)[i] : ((const int*)p)[i];
}

__device__ __forceinline__ ushort4 f4_to_h4(float4 v) {
    ushort4 r;
    r.x = __half_as_ushort(__float2half_rn(v.x));
    r.y = __half_as_ushort(__float2half_rn(v.y));
    r.z = __half_as_ushort(__float2half_rn(v.z));
    r.w = __half_as_ushort(__float2half_rn(v.w));
    return r;
}

// ---------------------------------------------------------------------------
// Scatter: pass A histograms dst buckets (LDS), one global atomic per
// (block,bucket) reserves a contiguous chunk, pass B re-reads edges (L2/L3
// warm) and writes pairs into the chunk. gcur must be zeroed.
// ---------------------------------------------------------------------------
__global__ __launch_bounds__(TPB) void p3_scatter(const void* __restrict__ ei,
                                                  long long E,
                                                  int* __restrict__ gcur,
                                                  int* __restrict__ pairs) {
    __shared__ int cnt[TPB];
    __shared__ int cur2[TPB];
    __shared__ int s_is64;
    int t = threadIdx.x;
    if (t < 64) {
        const unsigned int* w = (const unsigned int*)ei;
        unsigned long long m = __ballot(w[2 * t + 1] != 0u);
        if (t == 0) s_is64 = (m == 0ull) ? 1 : 0;
    }
    cnt[t] = 0;
    __syncthreads();
    const int is64 = s_is64;
    long long chunk = (E + SC_BLOCKS - 1) / SC_BLOCKS;
    long long s0 = (long long)blockIdx.x * chunk;
    long long s1 = (s0 + chunk < E) ? s0 + chunk : E;

    for (long long e = s0 + t; e < s1; e += TPB) {       // pass A: count
        int d = ld_idx(ei, E + e, is64);
        atomicAdd(&cnt[d >> 8], 1);
    }
    __syncthreads();
    if (cnt[t]) cur2[t] = (t << CAPSH) + atomicAdd(&gcur[t], cnt[t]);
    __syncthreads();
    for (long long e = s0 + t; e < s1; e += TPB) {       // pass B: write
        int sv = ld_idx(ei, e, is64);
        int d  = ld_idx(ei, E + e, is64);
        int pos = atomicAdd(&cur2[d >> 8], 1);
        pairs[pos] = (sv << 8) | (d & 255);
    }
}

// ---------------------------------------------------------------------------
// One block per bucket: degree count (LDS atomics) -> pad-to-8 256-wide scan
// -> meta, csr scatter via LDS cursors + pad with index N, then
// z0 = fp16(dis * x) for this bucket's 256 nodes. Block 0 zeroes z0 row N.
// ---------------------------------------------------------------------------
__global__ __launch_bounds__(TPB) void p4_fill(const int* __restrict__ pairs,
                                               const int* __restrict__ gcur,
                                               const float* __restrict__ x,
                                               int2* __restrict__ meta,
                                               int* __restrict__ csr,
                                               ushort4* __restrict__ z0, int N) {
    __shared__ int ldeg[TPB];
    __shared__ int ssc[TPB];
    __shared__ int cur[TPB];
    __shared__ float fdis[TPB];
    int t = threadIdx.x;
    int b = blockIdx.x;
    int base = b << CAPSH;
    int ecnt = gcur[b];                          // real edges in this bucket
    ldeg[t] = 0;
    __syncthreads();
    for (int e = base + t; e < base + ecnt; e += TPB)
        atomicAdd(&ldeg[pairs[e] & 255], 1);
    __syncthreads();
    int dv = ldeg[t];
    int pv = (dv + 7) & ~7;                      // padded to multiple of 8
    ssc[t] = pv;
    __syncthreads();
    for (int off = 1; off < TPB; off <<= 1) {
        int u = 0;
        if (t >= off) u = ssc[t - off];
        __syncthreads();
        ssc[t] += u;
        __syncthreads();
    }
    int o = base + ssc[t] - pv;                  // absolute padded offset
    cur[t] = o;
    float dd = rsqrtf((float)(dv + 1));          // +1 self loop
    fdis[t] = dd;
    int node = (b << 8) + t;
    if (node < N)
        meta[node] = make_int2((o << 8) | (pv >> 3), __float_as_int(dd));
    __syncthreads();
    for (int e = base + t; e < base + ecnt; e += TPB) {
        int p = pairs[e];
        int pos = atomicAdd(&cur[p & 255], 1);
        csr[pos] = p >> 8;
    }
    for (int e = o + dv; e < o + pv; ++e) csr[e] = N;   // pad with zero row

    // z0 conversion: 16 passes, 16 nodes each, coalesced float4 reads.
    int ni = t >> 4, c = t & 15;
    for (int p = 0; p < 16; ++p) {
        int nd = (b << 8) + p * 16 + ni;
        if (nd < N) {
            float dvv = fdis[p * 16 + ni];
            float4 h = ((const float4*)x)[(size_t)nd * 16 + c];
            float4 r = {h.x * dvv, h.y * dvv, h.z * dvv, h.w * dvv};
            z0[(size_t)nd * 16 + c] = f4_to_h4(r);
        }
    }
    if (b == 0 && t < 16) z0[(size_t)N * 16 + t] = make_ushort4(0, 0, 0, 0);
}

// ---------------------------------------------------------------------------
// Gather building blocks
// ---------------------------------------------------------------------------

#if __has_builtin(__builtin_amdgcn_fdot2) && __has_builtin(__builtin_amdgcn_perm)
#define GCN_DOT2 1
#else
#define GCN_DOT2 0
#endif

// Accumulate the 8 features of TWO fp16 rows into f32 acc.
// perm packs (rowA.h_j, rowB.h_j) into one half2; fdot2 with (1,1) adds both
// halves into the f32 accumulator: 4 inst per 2 rows x 2 features (vs 8).
__device__ __forceinline__ void accum_row_pair(const u16x8& ra, const u16x8& rb,
                                               f32x8& acc) {
#if GCN_DOT2
    u32x4 a = __builtin_bit_cast(u32x4, ra);
    u32x4 b = __builtin_bit_cast(u32x4, rb);
    const h16x2 one = {(_Float16)1.0f, (_Float16)1.0f};
    #pragma unroll
    for (int j = 0; j < 4; ++j) {
        unsigned p0 = __builtin_amdgcn_perm(a[j], b[j], 0x05040100u); // h0 pair
        unsigned p1 = __builtin_amdgcn_perm(a[j], b[j], 0x07060302u); // h1 pair
        acc[2 * j]     = __builtin_amdgcn_fdot2(__builtin_bit_cast(h16x2, p0),
                                                one, acc[2 * j], false);
        acc[2 * j + 1] = __builtin_amdgcn_fdot2(__builtin_bit_cast(h16x2, p1),
                                                one, acc[2 * j + 1], false);
    }
#else
    #pragma unroll
    for (int i = 0; i < 8; ++i)
        acc[i] += __half2float(__ushort_as_half(ra[i])) +
                  __half2float(__ushort_as_half(rb[i]));
#endif
}

__device__ __forceinline__ void accum_batch(const u16x8 (&R)[8], f32x8& acc) {
    #pragma unroll
    for (int k = 0; k < 8; k += 2) accum_row_pair(R[k], R[k + 1], acc);
}

// Issue the 8 independent 16B row-chunk loads of one batch (indices via shfl
// from the 8-lane group's coalesced csr read). Fully unrolled: static regs.
__device__ __forceinline__ void load_batch(const u16x8* __restrict__ z8,
                                           u16x8 (&R)[8], int idx, int c,
                                           int base) {
    #pragma unroll
    for (int k = 0; k < 8; ++k) {
        int s = __shfl(idx, base + k);
        R[k] = z8[(size_t)s * 8 + c];
    }
}

// Pipelined cooperative gather (PADDED csr): ping-pong row buffers A/B.
// While batch bt accumulates (VALU), batch bt+1's 8 row loads are already in
// flight; csr indices are prefetched 2 batches ahead so the shfl never waits
// on a fresh csr load. Doubles per-wave outstanding rows at same occupancy.
__device__ __forceinline__ f32x8 gather_rows(const u16x8* __restrict__ z8,
                                             const int* __restrict__ csr,
                                             int start, int nbatch, int c,
                                             f32x8 acc) {
    const int base = threadIdx.x & 56;           // 8-lane group base in wave
    if (nbatch <= 0) return acc;
    u16x8 A[8], B[8];
    int idx0 = csr[start + c];
    int idx_n = (nbatch > 1) ? csr[start + 8 + c] : 0;   // batch 1 idx
    load_batch(z8, A, idx0, c, base);
    int bt = 0;
    for (;;) {
        // invariant: A = rows of batch bt, idx_n = csr idx of batch bt+1
        int idx_f = (bt + 2 < nbatch) ? csr[start + (bt + 2) * 8 + c] : 0;
        if (bt + 1 < nbatch) load_batch(z8, B, idx_n, c, base);
        accum_batch(A, acc);
        if (++bt >= nbatch) break;
        // B = rows of batch bt, idx_f = csr idx of batch bt+1
        int idx_f2 = (bt + 2 < nbatch) ? csr[start + (bt + 2) * 8 + c] : 0;
        if (bt + 1 < nbatch) load_batch(z8, A, idx_f, c, base);
        accum_batch(B, acc);
        if (++bt >= nbatch) break;
        idx_n = idx_f2;
    }
    return acc;
}

// Shfl-based mm for 8-lane groups: lane c holds features 8c..8c+7 of its
// node (f32x8); broadcast via __shfl; lane c accumulates output cols
// 8c..8c+7. Per-k Ws reads are 2 consecutive float4s (256 B/group contiguous,
// broadcast across groups -> conflict-free).
__device__ __forceinline__ f32x8 shfl_mm8(f32x8 s, const float4* Ws4, int c) {
    const int base = threadIdx.x & 56;
    f32x8 u = {0.f, 0.f, 0.f, 0.f, 0.f, 0.f, 0.f, 0.f};
    #pragma unroll
    for (int q = 0; q < 8; ++q) {
        #pragma unroll
        for (int r = 0; r < 8; ++r) {
            float hv = __shfl(s[r], base + q);   // feature q*8+r
            float4 w0 = Ws4[(q * 8 + r) * 16 + 2 * c];
            float4 w1 = Ws4[(q * 8 + r) * 16 + 2 * c + 1];
            u[0] = fmaf(hv, w0.x, u[0]);
            u[1] = fmaf(hv, w0.y, u[1]);
            u[2] = fmaf(hv, w0.z, u[2]);
            u[3] = fmaf(hv, w0.w, u[3]);
            u[4] = fmaf(hv, w1.x, u[4]);
            u[5] = fmaf(hv, w1.y, u[5]);
            u[6] = fmaf(hv, w1.z, u[6]);
            u[7] = fmaf(hv, w1.w, u[7]);
        }
    }
    return u;
}

__device__ __forceinline__ u16x8 f8_to_h8(f32x8 v) {
    u16x8 r;
    #pragma unroll
    for (int i = 0; i < 8; ++i)
        r[i] = __half_as_ushort(__float2half_rn(v[i]));
    return r;
}

// ---------------------------------------------------------------------------
// Layer: s = z_v + Agg z_u (gather); u = s @ W; zout = fp16(dis*relu(dis*u+b)).
// 32 nodes/block, 8 threads/node. Only W in LDS (16 KB).
// Barrier placement: sync right after Ws staging (uniform), BEFORE the
// gather -- waves then flow gather->mm unsynchronized, overlapping VMEM and
// LDS phases across the CU instead of lockstepping them.
// ---------------------------------------------------------------------------
__global__ __launch_bounds__(TPB) void layer_mm(const u16x8* __restrict__ z,
                                                const int* __restrict__ csr,
                                                const int2* __restrict__ meta,
                                                const float* __restrict__ b,
                                                const float* __restrict__ W,
                                                u16x8* __restrict__ zout, int n) {
    __shared__ float Ws[64 * 64];
    int t = threadIdx.x;
    float4* Ws4 = (float4*)Ws;
    const float4* W4g = (const float4*)W;
    #pragma unroll
    for (int i = 0; i < 4; ++i) Ws4[t + i * TPB] = W4g[t + i * TPB];

    if (blockIdx.x == 0 && t < 8) {              // zero row N for next layer
        u16x8 zz = {0, 0, 0, 0, 0, 0, 0, 0};
        zout[(size_t)n * 8 + t] = zz;
    }
    __syncthreads();                             // Ws staged; no sync after this

    int wave = t >> 6, lane = t & 63;
    int g = lane >> 3, c = lane & 7;
    int node = blockIdx.x * 32 + wave * 8 + g;
    f32x8 s = {0.f, 0.f, 0.f, 0.f, 0.f, 0.f, 0.f, 0.f};
    float dv = 0.f;
    if (node < n) {
        int2 m = meta[node];
        int start = ((unsigned)m.x) >> 8;
        int nbatch = m.x & 255;
        dv = __int_as_float(m.y);
        u16x8 v = z[(size_t)node * 8 + c];       // self-loop term z_v
        #pragma unroll
        for (int i = 0; i < 8; ++i) s[i] = __half2float(__ushort_as_half(v[i]));
        s = gather_rows(z, csr, start, nbatch, c, s);
    }
    f32x8 u = shfl_mm8(s, Ws4, c);
    if (node < n) {
        float4 b0 = ((const float4*)b)[2 * c];
        float4 b1 = ((const float4*)b)[2 * c + 1];
        f32x8 r;
        r[0] = fmaxf(fmaf(dv, u[0], b0.x), 0.f) * dv;
        r[1] = fmaxf(fmaf(dv, u[1], b0.y), 0.f) * dv;
        r[2] = fmaxf(fmaf(dv, u[2], b0.z), 0.f) * dv;
        r[3] = fmaxf(fmaf(dv, u[3], b0.w), 0.f) * dv;
        r[4] = fmaxf(fmaf(dv, u[4], b1.x), 0.f) * dv;
        r[5] = fmaxf(fmaf(dv, u[5], b1.y), 0.f) * dv;
        r[6] = fmaxf(fmaf(dv, u[6], b1.z), 0.f) * dv;
        r[7] = fmaxf(fmaf(dv, u[7], b1.w), 0.f) * dv;
        zout[(size_t)node * 8 + c] = f8_to_h8(r);    // z_{l+1}
    }
}

// ---------------------------------------------------------------------------
// Final: s = gather(z2); h = relu(dis*(s@W2)+b2); out = h @ linW + linb.
// Second mm: lane c computes output col c (all 8 lanes active).
// Same early-barrier placement as layer_mm.
// ---------------------------------------------------------------------------
__global__ __launch_bounds__(TPB) void layer_final(const u16x8* __restrict__ z,
                                                   const int* __restrict__ csr,
                                                   const int2* __restrict__ meta,
                                                   const float* __restrict__ b,
                                                   const float* __restrict__ W,
                                                   const float* __restrict__ Wl,
                                                   const float* __restrict__ bl,
                                                   float* __restrict__ out, int n) {
    __shared__ float Ws[64 * 64];
    __shared__ float Wls[64 * 8];
    __shared__ float bls[8];
    int t = threadIdx.x;
    float4* Ws4 = (float4*)Ws;
    const float4* W4g = (const float4*)W;
    #pragma unroll
    for (int i = 0; i < 4; ++i) Ws4[t + i * TPB] = W4g[t + i * TPB];
    if (t < 128) ((float4*)Wls)[t] = ((const float4*)Wl)[t];
    if (t < 8) bls[t] = bl[t];
    __syncthreads();                             // Ws/Wls/bls staged

    int wave = t >> 6, lane = t & 63;
    int g = lane >> 3, c = lane & 7;
    int node = blockIdx.x * 32 + wave * 8 + g;
    f32x8 s = {0.f, 0.f, 0.f, 0.f, 0.f, 0.f, 0.f, 0.f};
    float dv = 0.f;
    if (node < n) {
        int2 m = meta[node];
        int start = ((unsigned)m.x) >> 8;
        int nbatch = m.x & 255;
        dv = __int_as_float(m.y);
        u16x8 v = z[(size_t)node * 8 + c];
        #pragma unroll
        for (int i = 0; i < 8; ++i) s[i] = __half2float(__ushort_as_half(v[i]));
        s = gather_rows(z, csr, start, nbatch, c, s);
    }
    f32x8 u = shfl_mm8(s, Ws4, c);
    float4 b0 = ((const float4*)b)[2 * c];
    float4 b1 = ((const float4*)b)[2 * c + 1];
    f32x8 h;
    h[0] = fmaxf(fmaf(dv, u[0], b0.x), 0.f);
    h[1] = fmaxf(fmaf(dv, u[1], b0.y), 0.f);
    h[2] = fmaxf(fmaf(dv, u[2], b0.z), 0.f);
    h[3] = fmaxf(fmaf(dv, u[3], b0.w), 0.f);
    h[4] = fmaxf(fmaf(dv, u[4], b1.x), 0.f);
    h[5] = fmaxf(fmaf(dv, u[5], b1.y), 0.f);
    h[6] = fmaxf(fmaf(dv, u[6], b1.z), 0.f);
    h[7] = fmaxf(fmaf(dv, u[7], b1.w), 0.f);

    // second mm (64 -> 8): lane c computes output col c.
    const int base = threadIdx.x & 56;
    float acc = bls[c];
    #pragma unroll
    for (int q = 0; q < 8; ++q) {
        #pragma unroll
        for (int r = 0; r < 8; ++r) {
            float hv = __shfl(h[r], base + q);   // feature q*8+r
            acc = fmaf(hv, Wls[(q * 8 + r) * 8 + c], acc);
        }
    }
    if (node < n) out[(size_t)node * 8 + c] = acc;
}

extern "C" void kernel_launch(void* const* d_in, const int* in_sizes, int n_in,
                              void* d_out, int out_size, void* d_ws, size_t ws_size,
                              hipStream_t stream) {
    const float* x  = (const float*)d_in[0];
    const void*  ei = d_in[1];
    const float* W0 = (const float*)d_in[2];
    const float* b0 = (const float*)d_in[3];
    const float* W1 = (const float*)d_in[4];
    const float* b1 = (const float*)d_in[5];
    const float* W2 = (const float*)d_in[6];
    const float* b2 = (const float*)d_in[7];
    const float* Wl = (const float*)d_in[8];
    const float* bl = (const float*)d_in[9];

    const long long E = in_sizes[1] / 2;                 // 800000
    const int dh = in_sizes[3];                          // 64
    const int din = in_sizes[2] / dh;                    // 64
    const int N = in_sizes[0] / din;                     // 50000
    const int nb = (N + 255) >> 8;                       // 196 buckets

    // Workspace carve (256-aligned): ~39 MB total
    char* ws = (char*)d_ws;
    size_t off = 0;
    auto alloc = [&](size_t bytes) -> char* {
        char* r = ws + off;
        off += (bytes + 255) & ~(size_t)255;
        return r;
    };
    int*   gcur    = (int*)  alloc(1024);
    int2*  meta    = (int2*) alloc((size_t)N * 8);
    int*   pairs   = (int*)  alloc((size_t)nb * CAP * 4);       // 12.8 MB
    int*   csr     = (int*)  alloc((size_t)nb * CAP * 4);       // 12.8 MB
    u16x8* zbA     = (u16x8*)alloc((size_t)(N + 1) * 64 * 2);   // fp16 rows (+zero row)
    u16x8* zbB     = (u16x8*)alloc((size_t)(N + 1) * 64 * 2);

    // --- preprocessing ---
    hipMemsetAsync(gcur, 0, 256 * sizeof(int), stream);
    p3_scatter<<<SC_BLOCKS, TPB, 0, stream>>>(ei, E, gcur, pairs);
    p4_fill<<<nb, TPB, 0, stream>>>(pairs, gcur, x, meta, csr,
                                    (ushort4*)zbA, N);

    // --- 3 layers: gather -> mm -> relu ---
    const int gL = (N + 31) / 32;                        // 1563
    layer_mm<<<gL, TPB, 0, stream>>>(zbA, csr, meta, b0, W0, zbB, N);
    layer_mm<<<gL, TPB, 0, stream>>>(zbB, csr, meta, b1, W1, zbA, N);
    layer_final<<<gL, TPB, 0, stream>>>(zbA, csr, meta, b2, W2, Wl, bl,
                                        (float*)d_out, N);
}